// Round 11
// baseline (193.817 us; speedup 1.0000x reference)
//
#include <hip/hip_runtime.h>

typedef _Float16 f16x8 __attribute__((ext_vector_type(8)));
typedef _Float16 f16x4 __attribute__((ext_vector_type(4)));
typedef short s16x4 __attribute__((ext_vector_type(4)));
typedef float f32x4 __attribute__((ext_vector_type(4)));

#define MFMA_K32(a, b, c) __builtin_amdgcn_mfma_f32_16x16x32_f16(a, b, c, 0, 0, 0)
#define MFMA_BF(a, b, c)  __builtin_amdgcn_mfma_f32_16x16x16bf16_1k(a, b, c, 0, 0, 0)

// B=8, N=3136, C=256, Ci=128, M=1568, NT=25088 rows. I/O fp32.
// Fragment-major internals (every hot load = base + lane*16B):
//   theta_f/y_f [1568 tiles][kc 4][lane 64][8]      (f16)
//   phi_f [8][chunk 49][kvt 2][kc 4][lane 64][8]    (f16)
//   g_f   [8][chunk 49][ct 8][lane 64][8]           (bf16)
//   wt_f  [3][ct 8][kc 8][lane 64][8], wf_f [2][ct 8][kc 4][lane 64][8]
// Softmax: static-shift (no online max): p = exp2(s*log2e - 104), P/V bf16.
// k_attn: R8 config (4 waves x 1 m-tile, grid 392) -- measured optimum.
// k_proj: LDS-staged coalesced x loads (fixes 16-row x-fragment scatter).

__device__ __forceinline__ unsigned f2bf_rne(float f) {
    unsigned u = __float_as_uint(f);
    return (u + 0x7FFFu + ((u >> 16) & 1u)) >> 16;
}
__device__ __forceinline__ int bfpack_rtz(float lo, float hi) {
    return (int)((__float_as_uint(hi) & 0xFFFF0000u) | (__float_as_uint(lo) >> 16));
}

// ---------------------------------------------------------------------------
// Prep: weights fp32 -> f16, fragment-major.  grid 512, block 256.
// ---------------------------------------------------------------------------
__global__ void k_prep(const float* __restrict__ wt, const float* __restrict__ wp,
                       const float* __restrict__ wg, const float* __restrict__ wf,
                       _Float16* __restrict__ wt_f, _Float16* __restrict__ wf_f) {
    int i = blockIdx.x * 256 + threadIdx.x;  // 0..131071
    int w = i >> 15, idx = i & 32767;
    if (w < 3) {
        const float* src = (w == 0) ? wt : (w == 1) ? wp : wg;
        int k = idx >> 7, n = idx & 127;
        int ct = n >> 4, tt = n & 15, kc = k >> 5, qq = (k >> 3) & 3, jj = k & 7;
        wt_f[((w * 8 + ct) * 8 + kc) * 512 + (qq * 16 + tt) * 8 + jj] = (_Float16)src[idx];
    } else {
        int k = idx >> 8, n = idx & 255;
        int cb = n >> 7, ct = (n >> 4) & 7, tt = n & 15;
        int kc = k >> 5, qq = (k >> 3) & 3, jj = k & 7;
        wf_f[((cb * 8 + ct) * 4 + kc) * 512 + (qq * 16 + tt) * 8 + jj] = (_Float16)wf[idx];
    }
}

// ---------------------------------------------------------------------------
// Fused projections, v2: block = 256 thr / 64 rows (4 waves x 1 m-tile).
// x tile loaded fully-coalesced (16 x 4KB bursts), fp32->f16 in-reg, staged
// to LDS (row stride 264 f16: 16B-aligned, 2-way banks = free); A-frags read
// from LDS. Weight B-frags coalesced from L2. Epilogues fragment-major.
// One block == one pooled KV chunk (64 rows -> 32 pooled).  grid 392.
// ---------------------------------------------------------------------------
__global__ __launch_bounds__(256) void k_proj(
    const float* __restrict__ x,        // [25088][256] fp32
    const _Float16* __restrict__ wt_f,  // [3][8][8][512]
    _Float16* __restrict__ theta_f,     // [1568][2048]
    _Float16* __restrict__ phi_f,       // [8][49][4096]
    short* __restrict__ g_f)            // [8][49][4096] bf16
{
    const int blk  = blockIdx.x;        // 392 = 8 batches x 49 chunks
    const int r0   = blk * 64;
    const int wave = threadIdx.x >> 6;
    const int lane = threadIdx.x & 63;
    const int q = lane >> 4, t = lane & 15;
    const int tid = threadIdx.x;

    __shared__ __align__(16) _Float16 x_lds[64 * 264];  // 33 KB, stride 264

    // ---- stage x: 64 KB fp32, fully coalesced; convert to f16
    const float* xb = x + r0 * 256;
#pragma unroll
    for (int it = 0; it < 16; ++it) {
        const int f = it * 1024 + tid * 4;       // flat element in 64x256 tile
        f32x4 v = *(const f32x4*)(xb + f);
        f16x4 h;
        h[0] = (_Float16)v[0]; h[1] = (_Float16)v[1];
        h[2] = (_Float16)v[2]; h[3] = (_Float16)v[3];
        const int row = f >> 8, col = f & 255;
        *(f16x4*)(&x_lds[row * 264 + col]) = h;
    }
    __syncthreads();

    // ---- A-frags from LDS: row = wave*16 + t, k = kc*32 + q*8 + j
    f16x8 af[8];
#pragma unroll
    for (int kc = 0; kc < 8; ++kc)
        af[kc] = *(const f16x8*)(&x_lds[(wave * 16 + t) * 264 + kc * 32 + q * 8]);

    const f32x4 zero = {0.f, 0.f, 0.f, 0.f};
    f32x4 acc[3][8];
#pragma unroll
    for (int w = 0; w < 3; ++w)
#pragma unroll
        for (int ct = 0; ct < 8; ++ct) acc[w][ct] = zero;

#pragma unroll
    for (int w = 0; w < 3; ++w)
#pragma unroll
        for (int ct = 0; ct < 8; ++ct) {
            const _Float16* Wc = wt_f + ((w * 8 + ct) * 8) * 512 + lane * 8;
#pragma unroll
            for (int kc = 0; kc < 8; ++kc)
                acc[w][ct] = MFMA_K32(af[kc], *(const f16x8*)(Wc + kc * 512), acc[w][ct]);
        }

    // ---- theta -> fragment-major tile (global tile = blk*4 + wave)
    _Float16* tb = theta_f + (blk * 4 + wave) * 2048;
#pragma unroll
    for (int ct = 0; ct < 8; ++ct) {
        const int off = (ct >> 1) * 512 + ((ct & 1) * 2 + (t >> 3)) * 128 + (t & 7);
#pragma unroll
        for (int r = 0; r < 4; ++r)
            tb[off + (q * 4 + r) * 8] = (_Float16)acc[0][ct][r];
    }

    // ---- pooled epilogues: block covers exactly chunk = blk%49 of batch blk/49
    const int b     = blk / 49;
    const int chunk = blk % 49;
    const int h     = wave >> 1;             // bit4 of pooled row in chunk
    const int ttp   = (wave & 1) * 8 + q * 2;  // kv' & 15 (even)

    _Float16* pcb = phi_f + (b * 49 + chunk) * 4096;
#pragma unroll
    for (int ct = 0; ct < 8; ++ct) {
        const int kc = ct >> 1;
        const int qq = (ct & 1) * 2 + (t >> 3);
        const int j  = t & 7;
        const int off = (h * 4 + kc) * 512 + (qq * 16 + ttp) * 8 + j;
        pcb[off]     = (_Float16)fmaxf(acc[1][ct][0], acc[1][ct][1]);
        pcb[off + 8] = (_Float16)fmaxf(acc[1][ct][2], acc[1][ct][3]);
    }

    short* gcb = g_f + (b * 49 + chunk) * 4096;
    const int qv  = (wave & 1) * 2 + (q >> 1);  // kv' >> 2
    const int jj0 = (q & 1) * 2;                // kv' & 3 (even)
#pragma unroll
    for (int ct = 0; ct < 8; ++ct) {
        unsigned lo = f2bf_rne(fmaxf(acc[2][ct][0], acc[2][ct][1]));
        unsigned hi = f2bf_rne(fmaxf(acc[2][ct][2], acc[2][ct][3]));
        *(unsigned*)(gcb + ct * 512 + (qv * 16 + t) * 8 + h * 4 + jj0) = lo | (hi << 16);
    }
}

// ---------------------------------------------------------------------------
// Attention (R8 config, measured optimum): Q-split, block = 64 Q rows
// (wave w owns m-tile w), 4 waves share the 16KB KV chunk via double-buffered
// LDS; reg prefetch overlaps compute; one barrier per chunk.
// grid 392 (8 batches x 49), block 256.
// ---------------------------------------------------------------------------
__global__ __launch_bounds__(256) void k_attn(
    const _Float16* __restrict__ theta_f,  // [1568][2048]
    const _Float16* __restrict__ phi_f,    // [8][49][4096]
    const short* __restrict__ g_f,         // [8][49][4096] bf16
    _Float16* __restrict__ y_f)            // [1568][2048]
{
    const int blk  = blockIdx.x;          // 392 = 8 batches x 49
    const int b    = blk & 7;             // XCD affinity
    const int blkm = blk >> 3;            // 0..48
    const int wave = threadIdx.x >> 6;
    const int lane = threadIdx.x & 63;
    const int q = lane >> 4, t = lane & 15;

    __shared__ __align__(16) _Float16 kv[2][8192];  // 32 KB: [phi 4096 | g 4096]

    const int tIdx = b * 196 + blkm * 4 + wave;     // this wave's m-tile
    const _Float16* ph = phi_f + b * 200704;
    const _Float16* gt = (const _Float16*)(g_f + b * 200704);

    f16x8 qf[4];
#pragma unroll
    for (int kc = 0; kc < 4; ++kc)
        qf[kc] = *(const f16x8*)(theta_f + tIdx * 2048 + kc * 512 + lane * 8);

    const f32x4 zero = {0.f, 0.f, 0.f, 0.f};
    f32x4 o[8];
#pragma unroll
    for (int ct = 0; ct < 8; ++ct) o[ct] = zero;
    float lsum = 0.f;
    const float L2E = 1.44269504f, SHIFT = 104.0f;

    // staging: wave w copies 4KB quarter of the 16KB chunk
    const _Float16* src0 = (wave < 2) ? (ph + wave * 2048) : (gt + (wave - 2) * 2048);
    const int doff = wave * 2048;

    f16x8 sr[4];
#pragma unroll
    for (int j = 0; j < 4; ++j)
        sr[j] = *(const f16x8*)(src0 + j * 512 + lane * 8);
#pragma unroll
    for (int j = 0; j < 4; ++j)
        *(f16x8*)(&kv[0][doff + j * 512 + lane * 8]) = sr[j];
    __syncthreads();

    for (int i = 0; i < 49; ++i) {
        if (i + 1 < 49) {
            const _Float16* s = src0 + (i + 1) * 4096;
#pragma unroll
            for (int j = 0; j < 4; ++j)
                sr[j] = *(const f16x8*)(s + j * 512 + lane * 8);
        }

        const _Float16* buf = &kv[i & 1][0];
        // S^T = phi @ theta^T (KV on C rows -> per-lane softmax axis)
        f32x4 st0 = zero, st1 = zero;
#pragma unroll
        for (int kc = 0; kc < 4; ++kc) {
            f16x8 a0 = *(const f16x8*)(buf + kc * 512 + lane * 8);
            f16x8 a1 = *(const f16x8*)(buf + (4 + kc) * 512 + lane * 8);
            st0 = MFMA_K32(a0, qf[kc], st0);
            st1 = MFMA_K32(a1, qf[kc], st1);
        }

        // p = exp2(s*log2e - SHIFT), accumulate l, pack P to bf16 (A-layout)
        f32x4 p0, p1;
#pragma unroll
        for (int r = 0; r < 4; ++r) {
            p0[r] = exp2f(st0[r] * L2E - SHIFT);
            p1[r] = exp2f(st1[r] * L2E - SHIFT);
        }
        lsum += ((p0[0] + p0[1]) + (p0[2] + p0[3]))
              + ((p1[0] + p1[1]) + (p1[2] + p1[3]));
        union { int i2[2]; s16x4 v; } u0, u1;
        u0.i2[0] = bfpack_rtz(p0[0], p0[1]);
        u0.i2[1] = bfpack_rtz(p0[2], p0[3]);
        u1.i2[0] = bfpack_rtz(p1[0], p1[1]);
        u1.i2[1] = bfpack_rtz(p1[2], p1[3]);

        // PV: O += P @ V; V (both kv-halves) in one b128 LDS read per ct
#pragma unroll
        for (int ct = 0; ct < 8; ++ct) {
            union { f16x8 f; s16x4 s[2]; } uv;
            uv.f = *(const f16x8*)(buf + 4096 + ct * 512 + lane * 8);
            o[ct] = MFMA_BF(u0.v, uv.s[0], o[ct]);
            o[ct] = MFMA_BF(u1.v, uv.s[1], o[ct]);
        }

        if (i + 1 < 49) {
            _Float16* d = &kv[(i + 1) & 1][doff];
#pragma unroll
            for (int j = 0; j < 4; ++j)
                *(f16x8*)(d + j * 512 + lane * 8) = sr[j];
        }
        __syncthreads();
    }

    // l per Q-row (row = lane t): reduce across quads once
    float lf = lsum;
    lf += __shfl_xor(lf, 16);
    lf += __shfl_xor(lf, 32);
    float inv[4];
#pragma unroll
    for (int r = 0; r < 4; ++r) inv[r] = 1.0f / __shfl(lf, q * 4 + r);

    // y_f fragment-major scatter (epilogue-once)
    _Float16* yb = y_f + tIdx * 2048;
#pragma unroll
    for (int ct = 0; ct < 8; ++ct) {
        const int off = (ct >> 1) * 512 + (2 * (ct & 1) + (t >> 3)) * 128 + (t & 7);
#pragma unroll
        for (int r = 0; r < 4; ++r)
            yb[off + (4 * q + r) * 8] = (_Float16)(o[ct][r] * inv[r]);
    }
}

// ---------------------------------------------------------------------------
// Final: out = x + y @ w_final (fp32), coalesced loads + LDS-transposed
// epilogue.  grid (392, 2), block 256.
// ---------------------------------------------------------------------------
__global__ __launch_bounds__(256) void k_final(
    const _Float16* __restrict__ y_f,   // [1568][2048]
    const _Float16* __restrict__ wf_f,  // [2][8][4][512]
    const float* __restrict__ x,        // [25088][256]
    float* __restrict__ out)            // [25088][256]
{
    const int r0   = blockIdx.x * 64;
    const int cb   = blockIdx.y;
    const int wave = threadIdx.x >> 6;
    const int lane = threadIdx.x & 63;
    const int q = lane >> 4, t = lane & 15;

    __shared__ float t_lds[4][16][132];

    const int tile = blockIdx.x * 4 + wave;
    f16x8 af[4];
#pragma unroll
    for (int kc = 0; kc < 4; ++kc)
        af[kc] = *(const f16x8*)(y_f + tile * 2048 + kc * 512 + lane * 8);

    const f32x4 zero = {0.f, 0.f, 0.f, 0.f};
    f32x4 acc[8];
#pragma unroll
    for (int ct = 0; ct < 8; ++ct) acc[ct] = zero;
#pragma unroll
    for (int ct = 0; ct < 8; ++ct) {
        const _Float16* Wc = wf_f + ((cb * 8 + ct) * 4) * 512 + lane * 8;
#pragma unroll
        for (int kc = 0; kc < 4; ++kc)
            acc[ct] = MFMA_K32(af[kc], *(const f16x8*)(Wc + kc * 512), acc[ct]);
    }

#pragma unroll
    for (int ct = 0; ct < 8; ++ct)
#pragma unroll
        for (int r = 0; r < 4; ++r)
            t_lds[wave][q * 4 + r][ct * 16 + t] = acc[ct][r];

    const int R0 = r0 + wave * 16;
#pragma unroll
    for (int p = 0; p < 4; ++p) {
        const int rr = p * 4 + q;
        const int c  = t * 8;
        f32x4 v0 = *(const f32x4*)&t_lds[wave][rr][c];
        f32x4 v1 = *(const f32x4*)&t_lds[wave][rr][c + 4];
        const float* xp = x + (R0 + rr) * 256 + cb * 128 + c;
        float* op = out + (R0 + rr) * 256 + cb * 128 + c;
        v0 += *(const f32x4*)xp;
        v1 += *(const f32x4*)(xp + 4);
        *(f32x4*)op = v0;
        *(f32x4*)(op + 4) = v1;
    }
}

// ---------------------------------------------------------------------------
extern "C" void kernel_launch(void* const* d_in, const int* in_sizes, int n_in,
                              void* d_out, int out_size, void* d_ws, size_t ws_size,
                              hipStream_t stream) {
    const float* x  = (const float*)d_in[0];
    const float* wt = (const float*)d_in[1];
    const float* wp = (const float*)d_in[2];
    const float* wg = (const float*)d_in[3];
    const float* wf = (const float*)d_in[4];
    float* out = (float*)d_out;

    _Float16* ws      = (_Float16*)d_ws;
    _Float16* wt_f    = ws;               //  98304
    _Float16* wf_f    = ws + 98304;       //  32768
    _Float16* theta_f = ws + 131072;      //  3211264
    _Float16* phi_f   = ws + 3342336;     //  1605632
    short*    g_f     = (short*)(ws + 4947968);  // 1605632
    _Float16* y_f     = ws + 6553600;     //  3211264
    // total 9764864 halves = ~18.6 MB

    k_prep <<<dim3(512),    256, 0, stream>>>(wt, wp, wg, wf, wt_f, wf_f);
    k_proj <<<dim3(392),    256, 0, stream>>>(x, wt_f, theta_f, phi_f, g_f);
    k_attn <<<dim3(392),    256, 0, stream>>>(theta_f, phi_f, g_f, y_f);
    k_final<<<dim3(392, 2), 256, 0, stream>>>(y_f, wf_f, x, out);
}